// Round 6
// baseline (2927.736 us; speedup 1.0000x reference)
//
#include <hip/hip_runtime.h>
#include <hip/hip_bf16.h>

typedef _Float16 half4v __attribute__((ext_vector_type(4)));
typedef _Float16 half8v __attribute__((ext_vector_type(8)));
typedef float f32x4 __attribute__((ext_vector_type(4)));

#define T_STEPS 256
#define BATCH 64
#define NHID 512
#define NINP 512
#define MROWS (T_STEPS * BATCH)          // 16384
#define KDIM (2 * NINP)                  // 1024
#define NOUT (2 * NHID + NHID)           // 1536

#define NGRP 16        // chain groups
#define CPG 4          // chains per group
#define WPG 16         // WGs per group (each owns 32 hidden dims)
#define DPW 32         // dims per WG

// ---------------------------------------------------------------- converts

__global__ __launch_bounds__(256) void k_convert_x(
    const float* __restrict__ inp, const float* __restrict__ sem,
    _Float16* __restrict__ xh) {
  int idx = blockIdx.x * 256 + threadIdx.x;
  const int G = MROWS * KDIM / 4;
  for (int g = idx; g < G; g += 2048 * 256) {
    int e = g * 4;
    int m = e >> 10, k = e & 1023;
    const float* src = (k < NINP) ? (inp + (size_t)m * NINP + k)
                                  : (sem + (size_t)m * NINP + (k - NINP));
    float4 v = *(const float4*)src;
    half4v o = { (_Float16)v.x, (_Float16)v.y, (_Float16)v.z, (_Float16)v.w };
    *(half4v*)(xh + (size_t)e) = o;
  }
}

// biasN folds BOTH the x-side and recurrent biases.
__global__ __launch_bounds__(256) void k_convert_w(
    const float* __restrict__ W_ioux, const float* __restrict__ W_fx,
    const float* __restrict__ b_ioux, const float* __restrict__ b_fx,
    const float* __restrict__ b_iouh, const float* __restrict__ b_Uh,
    _Float16* __restrict__ wbig, float* __restrict__ biasN) {
  int g = blockIdx.x * 256 + threadIdx.x;
  int e = g * 4;
  int n = e >> 10, k = e & 1023;
  const float* src = (n < 2 * NHID) ? (W_ioux + (size_t)n * KDIM + k)
                                    : (W_fx + (size_t)(n - 2 * NHID) * KDIM + k);
  float4 v = *(const float4*)src;
  half4v o = { (_Float16)v.x, (_Float16)v.y, (_Float16)v.z, (_Float16)v.w };
  *(half4v*)(wbig + (size_t)e) = o;
  if (g < NOUT)
    biasN[g] = (g < 2 * NHID) ? (b_ioux[g] + b_iouh[g])
                              : (b_fx[g - 2 * NHID] + b_Uh[g - 2 * NHID]);
}

__global__ __launch_bounds__(256) void k_convert_wrec(
    const float* __restrict__ W_iouh, const float* __restrict__ W_Uh,
    _Float16* __restrict__ wrec) {
  int g = blockIdx.x * 256 + threadIdx.x;
  int e = g * 4;
  const int NI = 2 * NHID * NHID;
  const float* src = (e < NI) ? (W_iouh + e) : (W_Uh + (e - NI));
  float4 v = *(const float4*)src;
  half4v o = { (_Float16)v.x, (_Float16)v.y, (_Float16)v.z, (_Float16)v.w };
  *(half4v*)(wrec + (size_t)e) = o;
}

// ---------------------------------------------------------------- GEMM

__device__ __forceinline__ void gload16(const void* g, void* l) {
  __builtin_amdgcn_global_load_lds(
      (const __attribute__((address_space(1))) unsigned int*)g,
      (__attribute__((address_space(3))) unsigned int*)l, 16, 0, 0);
}

__global__ __launch_bounds__(256) void gemm_bt(
    const _Float16* __restrict__ A, const _Float16* __restrict__ Bm,
    const float* __restrict__ biasN, float* __restrict__ C,
    int M, int N, int K) {
  __shared__ __align__(16) _Float16 As[128 * 32];
  __shared__ __align__(16) _Float16 Bs[128 * 32];
  const int tid = threadIdx.x;
  const int lane = tid & 63;
  const int w = tid >> 6;
  const int wr = w >> 1, wc = w & 1;
  const int nbm = M >> 7;
  const int bm = blockIdx.x % nbm, bn = blockIdx.x / nbm;
  const int m0 = bm << 7, n0 = bn << 7;
  const int lr = lane & 15, lh = lane >> 4;

  f32x4 acc[4][4] = {};

  for (int kk = 0; kk < K; kk += 32) {
#pragma unroll
    for (int c = 0; c < 2; ++c) {
      int L = (c * 256 + tid) * 16;
      int row = L >> 6, inrow = L & 63;
      gload16((const char*)A + ((size_t)(m0 + row) * K + kk) * 2 + inrow,
              (char*)As + L);
      gload16((const char*)Bm + ((size_t)(n0 + row) * K + kk) * 2 + inrow,
              (char*)Bs + L);
    }
    __syncthreads();
    half8v af[4], bf[4];
#pragma unroll
    for (int i = 0; i < 4; ++i)
      af[i] = *(const half8v*)&As[(wr * 64 + i * 16 + lr) * 32 + lh * 8];
#pragma unroll
    for (int i = 0; i < 4; ++i)
      bf[i] = *(const half8v*)&Bs[(wc * 64 + i * 16 + lr) * 32 + lh * 8];
#pragma unroll
    for (int i = 0; i < 4; ++i)
#pragma unroll
      for (int j = 0; j < 4; ++j)
        acc[i][j] = __builtin_amdgcn_mfma_f32_16x16x32_f16(af[i], bf[j], acc[i][j], 0, 0, 0);
    __syncthreads();
  }

#pragma unroll
  for (int i = 0; i < 4; ++i)
#pragma unroll
    for (int j = 0; j < 4; ++j) {
      int n = n0 + wc * 64 + j * 16 + lr;
      float bv = biasN[n];
#pragma unroll
      for (int q = 0; q < 4; ++q) {
        int m = m0 + wr * 64 + i * 16 + lh * 4 + q;
        C[(size_t)m * N + n] = acc[i][j][q] + bv;
      }
    }
}

// ---------------------------------------------------------------- recurrence
// Same dataflow as round 5, but ALL cross-WG communication is XCD-LOCAL:
// bid = xcd + 8*(g + 16*Ghi); group G = Ghi*8 + xcd. Each group's 16 WGs sit
// on ONE XCD (2 groups = 32 WGs = the XCD's 32 CUs). Relaxed agent atomics
// are coherent at the local XCD L2 (validated rounds 2-4; round 5 showed
// they are NOT coherent across XCDs -> stale replays). Weights (1.5 MB)
// stay L2-resident per XCD; flags/hbuf/partials live in the same L2.

__device__ __forceinline__ float dot8(half8v a, half8v b, float acc) {
  acc = __builtin_amdgcn_fdot2(__builtin_shufflevector(a, a, 0, 1),
                               __builtin_shufflevector(b, b, 0, 1), acc, false);
  acc = __builtin_amdgcn_fdot2(__builtin_shufflevector(a, a, 2, 3),
                               __builtin_shufflevector(b, b, 2, 3), acc, false);
  acc = __builtin_amdgcn_fdot2(__builtin_shufflevector(a, a, 4, 5),
                               __builtin_shufflevector(b, b, 4, 5), acc, false);
  acc = __builtin_amdgcn_fdot2(__builtin_shufflevector(a, a, 6, 7),
                               __builtin_shufflevector(b, b, 6, 7), acc, false);
  return acc;
}

__device__ __forceinline__ float sigm(float v) { return 1.f / (1.f + __expf(-v)); }

__device__ __forceinline__ void wait16(int* f, int need, int lane) {
  int v = need;
  if (lane < 16)
    v = __hip_atomic_load(&f[lane], __ATOMIC_RELAXED, __HIP_MEMORY_SCOPE_AGENT);
  while (__any(v < need)) {
    __builtin_amdgcn_s_sleep(2);
    if (lane < 16)
      v = __hip_atomic_load(&f[lane], __ATOMIC_RELAXED, __HIP_MEMORY_SCOPE_AGENT);
  }
}

__device__ __forceinline__ void st16a(unsigned short* p, _Float16 x) {
  __hip_atomic_store(p, __builtin_bit_cast(unsigned short, x),
                     __ATOMIC_RELAXED, __HIP_MEMORY_SCOPE_AGENT);
}

__global__ __launch_bounds__(256, 1) void recur6(
    const _Float16* __restrict__ Wrec, const float* __restrict__ hx,
    const float* __restrict__ proj, unsigned short* __restrict__ hbuf,
    float* __restrict__ partials, int* __restrict__ flags,
    float* __restrict__ out) {
  __shared__ __align__(16) _Float16 hsh[CPG][NHID];   // staged h_t (f16)
  __shared__ __align__(16) _Float16 rhsh[CPG][DPW];   // local r*h slice
  __shared__ float zsh[CPG][DPW];
  __shared__ float hfsh[CPG][DPW];                    // exact f32 h for Dg

  const int bid = blockIdx.x;
  // XCD-local mapping: all 16 WGs of a group share bid%8 -> one XCD L2.
  const int xcd = bid & 7;
  const int s = bid >> 3;            // 0..31
  const int g = s & 15;              // WG index within group
  const int G = ((s >> 4) << 3) + xcd;  // group id 0..15
  const int tid = threadIdx.x;
  const int lane = tid & 63;
  const int row8 = tid >> 3, okt = tid & 7;     // phase1: 32 rows x 8 K-slices
  const int i64 = tid >> 2, okt2 = tid & 3;     // phase2: 64 i x 4 k-slices

  int* pfl = flags + G * 32;                    // [0..15]
  int* hfl = flags + G * 32 + 16;               // [16..31]
  const _Float16* WU = Wrec + (size_t)1024 * 512;
  float* pbase = partials + (size_t)G * (WPG * CPG * NHID);   // [p][c][512]
  unsigned short* hbG = hbuf + (size_t)G * CPG * NHID;

  const int jz = g * DPW + row8;                // z weight row
  const int jr = 512 + g * DPW + row8;          // r weight row

  // ---- init: h_0 for Dg (f32) and full h_0 stage (f16)
  if (tid < CPG * DPW) {
    int c = tid >> 5, d = tid & 31;
    hfsh[c][d] = hx[(size_t)(G * CPG + c) * NHID + g * DPW + d];
  }
  {
    // stage full h_0 from hx: 2048 f16; thread handles 8
    int base = tid * 8;
    int c = base >> 9, d = base & 511;
    float4 v0 = *(const float4*)(hx + (size_t)(G * CPG + c) * NHID + d);
    float4 v1 = *(const float4*)(hx + (size_t)(G * CPG + c) * NHID + d + 4);
    half8v o = { (_Float16)v0.x, (_Float16)v0.y, (_Float16)v0.z, (_Float16)v0.w,
                 (_Float16)v1.x, (_Float16)v1.y, (_Float16)v1.z, (_Float16)v1.w };
    *(half8v*)&hsh[c][d] = o;
  }
  __syncthreads();

  for (int t = 0; t < T_STEPS; ++t) {
    // ---- flag-independent proj loads (issue before any wait)
    float pz[CPG], pr[CPG], pf = 0.f;
    if (okt == 0) {
#pragma unroll
      for (int c = 0; c < CPG; ++c) {
        const float* pb = proj + (size_t)(t * BATCH + G * CPG + c) * NOUT;
        pz[c] = pb[jz];
        pr[c] = pb[g * DPW + row8 + 512];
      }
    }
    if (tid < CPG * DPW) {
      int c = tid >> 5, d = tid & 31;
      pf = proj[(size_t)(t * BATCH + G * CPG + c) * NOUT + 1024 + g * DPW + d];
    }

    // ---- stage h_t (t>0: from hbuf via local-XCD L2)
    if (t > 0) {
      wait16(hfl, t, lane);
      asm volatile("" ::: "memory");
#pragma unroll
      for (int r = 0; r < 4; ++r) {
        unsigned v = __hip_atomic_load((const unsigned*)hbG + r * 256 + tid,
                                       __ATOMIC_RELAXED, __HIP_MEMORY_SCOPE_AGENT);
        ((unsigned*)hsh)[r * 256 + tid] = v;
      }
      __syncthreads();
    }

    // ---- phase 1: z,r rows for Dg (fused, shared h reads)
    float za[CPG] = {}, ra[CPG] = {};
#pragma unroll
    for (int it = 0; it < 8; ++it) {
      half8v wzv = *(const half8v*)(Wrec + (size_t)jz * 512 + it * 64 + okt * 8);
      half8v wrv = *(const half8v*)(Wrec + (size_t)jr * 512 + it * 64 + okt * 8);
#pragma unroll
      for (int c = 0; c < CPG; ++c) {
        half8v hv = *(const half8v*)&hsh[c][it * 64 + okt * 8];
        za[c] = dot8(wzv, hv, za[c]);
        ra[c] = dot8(wrv, hv, ra[c]);
      }
    }
#pragma unroll
    for (int c = 0; c < CPG; ++c) {
      za[c] += __shfl_xor(za[c], 1); za[c] += __shfl_xor(za[c], 2); za[c] += __shfl_xor(za[c], 4);
      ra[c] += __shfl_xor(ra[c], 1); ra[c] += __shfl_xor(ra[c], 2); ra[c] += __shfl_xor(ra[c], 4);
    }
    if (okt == 0) {
#pragma unroll
      for (int c = 0; c < CPG; ++c) {
        zsh[c][row8] = sigm(za[c] + pz[c]);
        float rv = sigm(ra[c] + pr[c]);
        rhsh[c][row8] = (_Float16)(rv * hfsh[c][row8]);
      }
    }
    __syncthreads();

    // ---- phase 2: K-split W_Uh partials (local rh, no wait)
    half8v rv[CPG];
#pragma unroll
    for (int c = 0; c < CPG; ++c)
      rv[c] = *(const half8v*)&rhsh[c][okt2 * 8];
#pragma unroll
    for (int q = 0; q < 8; ++q) {
      int i = q * 64 + i64;
      half8v wv = *(const half8v*)(WU + (size_t)i * 512 + g * DPW + okt2 * 8);
      float pa[CPG];
#pragma unroll
      for (int c = 0; c < CPG; ++c) {
        float a = dot8(wv, rv[c], 0.f);
        a += __shfl_xor(a, 1);
        a += __shfl_xor(a, 2);
        pa[c] = a;
      }
      if (okt2 == 0) {
#pragma unroll
        for (int c = 0; c < CPG; ++c)
          __hip_atomic_store(&pbase[(size_t)(g * CPG + c) * NHID + i], pa[c],
                             __ATOMIC_RELAXED, __HIP_MEMORY_SCOPE_AGENT);
      }
    }
    __syncthreads();                    // drain partial stores (vmcnt 0)
    if (tid == 0)
      __hip_atomic_store(&pfl[g], t + 1, __ATOMIC_RELAXED, __HIP_MEMORY_SCOPE_AGENT);

    // ---- wait all partials, update h for Dg
    wait16(pfl, t + 1, lane);
    asm volatile("" ::: "memory");
    if (tid < CPG * DPW) {
      int c = tid >> 5, d = tid & 31;
      int u = g * DPW + d;
      float s2 = 0.f;
#pragma unroll
      for (int p = 0; p < WPG; ++p)
        s2 += __hip_atomic_load(&pbase[(size_t)(p * CPG + c) * NHID + u],
                                __ATOMIC_RELAXED, __HIP_MEMORY_SCOPE_AGENT);
      float v = s2 + pf;
      float e = __expf(-2.f * fabsf(v));
      float th = (1.f - e) / (1.f + e);
      th = (v < 0.f) ? -th : th;
      float hold = hfsh[c][d];
      float hn = fmaf(zsh[c][d], th - hold, hold);
      hfsh[c][d] = hn;
      st16a(&hbG[(size_t)c * NHID + u], (_Float16)hn);
      out[(size_t)(t * BATCH + G * CPG + c) * NHID + u] = hn;
    }
    __syncthreads();                    // drain h stores
    if (tid == 0)
      __hip_atomic_store(&hfl[g], t + 1, __ATOMIC_RELAXED, __HIP_MEMORY_SCOPE_AGENT);
  }

  // ---- h_last
  if (tid < CPG * DPW) {
    int c = tid >> 5, d = tid & 31;
    out[(size_t)T_STEPS * BATCH * NHID + (size_t)(G * CPG + c) * NHID + g * DPW + d] =
        hfsh[c][d];
  }
}

// ---------------------------------------------------------------- launcher

extern "C" void kernel_launch(void* const* d_in, const int* in_sizes, int n_in,
                              void* d_out, int out_size, void* d_ws, size_t ws_size,
                              hipStream_t stream) {
  const float* inputs = (const float*)d_in[0];
  const float* sememe = (const float*)d_in[1];
  const float* hx     = (const float*)d_in[2];
  const float* W_ioux = (const float*)d_in[3];
  const float* b_ioux = (const float*)d_in[4];
  const float* W_iouh = (const float*)d_in[5];
  const float* b_iouh = (const float*)d_in[6];
  const float* W_fx   = (const float*)d_in[7];
  const float* b_fx   = (const float*)d_in[8];
  const float* W_Uh   = (const float*)d_in[9];
  const float* b_Uh   = (const float*)d_in[10];
  float* out = (float*)d_out;

  char* ws = (char*)d_ws;
  _Float16* xh = (_Float16*)ws;   ws += (size_t)MROWS * KDIM * 2;
  _Float16* wbig = (_Float16*)ws; ws += (size_t)NOUT * KDIM * 2;
  float* biasN = (float*)ws;      ws += (size_t)NOUT * 4;
  _Float16* wrec = (_Float16*)ws; ws += (size_t)(3 * NHID * NHID) * 2;
  float* proj = (float*)ws;       ws += (size_t)MROWS * NOUT * 4;
  unsigned short* hbuf = (unsigned short*)ws; ws += (size_t)BATCH * NHID * 2;
  float* partials = (float*)ws;   ws += (size_t)NGRP * WPG * CPG * NHID * 4; // 8 MB
  int* flags = (int*)ws;          ws += (size_t)NGRP * 32 * 4;

  hipMemsetAsync(flags, 0, (size_t)NGRP * 32 * 4, stream);
  k_convert_x<<<2048, 256, 0, stream>>>(inputs, sememe, xh);
  k_convert_w<<<(NOUT * KDIM / 4) / 256, 256, 0, stream>>>(
      W_ioux, W_fx, b_ioux, b_fx, b_iouh, b_Uh, wbig, biasN);
  k_convert_wrec<<<(3 * NHID * NHID / 4) / 256, 256, 0, stream>>>(W_iouh, W_Uh, wrec);
  gemm_bt<<<(MROWS / 128) * (NOUT / 128), 256, 0, stream>>>(
      xh, wbig, biasN, proj, MROWS, NOUT, KDIM);
  recur6<<<NGRP * WPG, 256, 0, stream>>>(wrec, hx, proj, hbuf, partials, flags, out);
}